// Round 1
// baseline (1827.585 us; speedup 1.0000x reference)
//
#include <hip/hip_runtime.h>
#include <math.h>

#define H 2048
#define IDIM 5632
#define NE 8
#define TT 2048            // tokens = 2*1024
#define LDW1 (2 * IDIM)    // 11264

typedef __bf16 bf16x8 __attribute__((ext_vector_type(8)));
typedef float f32x4 __attribute__((ext_vector_type(4)));

__device__ __forceinline__ unsigned short f2bf(float f) {
    unsigned int u = __builtin_bit_cast(unsigned int, f);
    u += 0x7FFFu + ((u >> 16) & 1u);   // round-to-nearest-even
    return (unsigned short)(u >> 16);
}

// ---------------- x (fp32) -> bf16 ----------------
__global__ void cvt_x_kernel(const float* __restrict__ x, unsigned short* __restrict__ xb) {
    int i = blockIdx.x * blockDim.x + threadIdx.x;   // one float4 per thread
    float4 v = reinterpret_cast<const float4*>(x)[i];
    ushort4 o;
    o.x = f2bf(v.x); o.y = f2bf(v.y); o.z = f2bf(v.z); o.w = f2bf(v.w);
    reinterpret_cast<ushort4*>(xb)[i] = o;
}

// ---------------- router: fp64 logits, softmax, top-2, lists ----------------
__global__ void router_kernel(const float* __restrict__ x, const float* __restrict__ gw,
                              float* __restrict__ topw, int* __restrict__ cnt,
                              int* __restrict__ list) {
    int t = blockIdx.x;
    int lane = threadIdx.x;           // 64 lanes
    const float* xt = x + (size_t)t * H;
    double acc[NE];
#pragma unroll
    for (int e = 0; e < NE; ++e) acc[e] = 0.0;
    for (int h = lane; h < H; h += 64) {
        float xv = xt[h];
#pragma unroll
        for (int e = 0; e < NE; ++e) acc[e] += (double)xv * (double)gw[e * H + h];
    }
#pragma unroll
    for (int e = 0; e < NE; ++e) {
#pragma unroll
        for (int off = 32; off > 0; off >>= 1)
            acc[e] += __shfl_xor(acc[e], off, 64);
    }
    if (lane == 0) {
        double mx = acc[0];
#pragma unroll
        for (int e = 1; e < NE; ++e) mx = acc[e] > mx ? acc[e] : mx;
        double ex[NE], s = 0.0;
#pragma unroll
        for (int e = 0; e < NE; ++e) { ex[e] = exp(acc[e] - mx); s += ex[e]; }
        int e0 = 0; double b0 = ex[0];
#pragma unroll
        for (int e = 1; e < NE; ++e) if (ex[e] > b0) { b0 = ex[e]; e0 = e; }
        int e1 = -1; double b1 = -1.0;
#pragma unroll
        for (int e = 0; e < NE; ++e) if (e != e0 && ex[e] > b1) { b1 = ex[e]; e1 = e; }
        float p0 = (float)(b0 / s), p1 = (float)(b1 / s);
        float w0 = p0 / (p0 + p1), w1 = p1 / (p0 + p1);
        topw[t * 2 + 0] = w0;
        topw[t * 2 + 1] = w1;
        int pos0 = atomicAdd(&cnt[e0], 1); list[e0 * TT + pos0] = t * 2 + 0;
        int pos1 = atomicAdd(&cnt[e1], 1); list[e1 * TT + pos1] = t * 2 + 1;
    }
}

// ---------------- tile map: group tile prefix sums ----------------
__global__ void setup_kernel(const int* __restrict__ cnt, int* __restrict__ tmap) {
    if (threadIdx.x == 0) {
        int acc0 = 0;
        tmap[0] = 0;
        for (int g = 0; g < 9; ++g) {
            int rows = (g == 0) ? TT : cnt[g - 1];
            tmap[10 + g] = rows;
            acc0 += (rows + 63) >> 6;
            tmap[g + 1] = acc0;
        }
        tmap[19] = 0;
    }
}

// ---------------- grouped GEMM1: gu = X @ Wgu, act = silu(g)*u (bf16) ----------------
__global__ __launch_bounds__(256)
void gemm1_kernel(const unsigned short* __restrict__ xb,
                  const float* __restrict__ base_gu,
                  const float* __restrict__ exp_gu,
                  const int* __restrict__ tmap,
                  const int* __restrict__ list,
                  unsigned short* __restrict__ actB,
                  unsigned short* __restrict__ actE) {
    __shared__ unsigned short lds_a[64 * 40];
    __shared__ unsigned short lds_b[2][64 * 40];
    __shared__ int s_arow[64];
    __shared__ int s_orow[64];
    __shared__ int sh[20];

    int tid = threadIdx.x;
    if (tid < 20) sh[tid] = tmap[tid];
    __syncthreads();
    int rt = blockIdx.x;
    if (rt >= sh[9]) return;
    int g = 0;
    while (rt >= sh[g + 1]) ++g;
    int rows_g = sh[10 + g];
    int row0 = (rt - sh[g]) * 64;
    int n0 = blockIdx.y * 64;

    if (tid < 64) {
        int r = row0 + tid;
        int arow = -1, orow = 0;
        if (r < rows_g) {
            if (g == 0) { arow = r; orow = r; }
            else { int entry = list[(g - 1) * TT + r]; arow = entry >> 1; orow = entry; }
        }
        s_arow[tid] = arow;
        s_orow[tid] = orow;
    }
    __syncthreads();

    const float* W = (g == 0) ? base_gu : (exp_gu + (size_t)(g - 1) * H * LDW1);
    unsigned short* actPtr = (g == 0) ? actB : actE;

    // A staging: thread -> (row tid>>2, k-chunk tid&3)
    int my_tok = s_arow[tid >> 2];
    const unsigned short* ap = xb + (size_t)(my_tok < 0 ? 0 : my_tok) * H + (tid & 3) * 8;
    int a_lds = (tid >> 2) * 40 + (tid & 3) * 8;

    // B staging: tid<128: half bh, 8k x 4n subblock
    int bh = (tid >> 6) & 1;
    int bs = tid & 63;
    int bkk = (bs >> 4) << 3;
    int bnq = bs & 15;
    const float* wp = W + (size_t)bkk * LDW1 + (size_t)bh * IDIM + n0 + bnq * 4;

    int wave = tid >> 6, lane = tid & 63;
    int wr = wave >> 1, wc = wave & 1;
    int a_off0 = (wr * 32 + (lane & 15)) * 40 + (lane >> 4) * 8;
    int b_off0 = (wc * 32 + (lane & 15)) * 40 + (lane >> 4) * 8;

    f32x4 acc[2][2][2];
#pragma unroll
    for (int h2 = 0; h2 < 2; ++h2)
#pragma unroll
        for (int fm = 0; fm < 2; ++fm)
#pragma unroll
            for (int fn = 0; fn < 2; ++fn)
                acc[h2][fm][fn] = (f32x4)(0.0f);

    for (int k0 = 0; k0 < H; k0 += 32) {
        uint4 av = make_uint4(0, 0, 0, 0);
        if (my_tok >= 0) av = *reinterpret_cast<const uint4*>(ap + k0);
        *reinterpret_cast<uint4*>(&lds_a[a_lds]) = av;

        if (tid < 128) {
            const float* wpk = wp + (size_t)k0 * LDW1;
            float wq[8][4];
#pragma unroll
            for (int r = 0; r < 8; ++r) {
                float4 t4 = *reinterpret_cast<const float4*>(wpk + (size_t)r * LDW1);
                wq[r][0] = t4.x; wq[r][1] = t4.y; wq[r][2] = t4.z; wq[r][3] = t4.w;
            }
#pragma unroll
            for (int c = 0; c < 4; ++c) {
                unsigned int p0 = (unsigned)f2bf(wq[0][c]) | ((unsigned)f2bf(wq[1][c]) << 16);
                unsigned int p1 = (unsigned)f2bf(wq[2][c]) | ((unsigned)f2bf(wq[3][c]) << 16);
                unsigned int p2 = (unsigned)f2bf(wq[4][c]) | ((unsigned)f2bf(wq[5][c]) << 16);
                unsigned int p3 = (unsigned)f2bf(wq[6][c]) | ((unsigned)f2bf(wq[7][c]) << 16);
                uint4 pk; pk.x = p0; pk.y = p1; pk.z = p2; pk.w = p3;
                *reinterpret_cast<uint4*>(&lds_b[bh][(bnq * 4 + c) * 40 + bkk]) = pk;
            }
        }
        __syncthreads();

        bf16x8 afr[2];
#pragma unroll
        for (int fm = 0; fm < 2; ++fm)
            afr[fm] = *reinterpret_cast<const bf16x8*>(&lds_a[a_off0 + fm * 16 * 40]);
#pragma unroll
        for (int h2 = 0; h2 < 2; ++h2) {
#pragma unroll
            for (int fn = 0; fn < 2; ++fn) {
                bf16x8 bfr = *reinterpret_cast<const bf16x8*>(&lds_b[h2][b_off0 + fn * 16 * 40]);
#pragma unroll
                for (int fm = 0; fm < 2; ++fm)
                    acc[h2][fm][fn] = __builtin_amdgcn_mfma_f32_16x16x32_bf16(
                        afr[fm], bfr, acc[h2][fm][fn], 0, 0, 0);
            }
        }
        __syncthreads();
    }

    int cq = lane >> 4, cr = lane & 15;
#pragma unroll
    for (int fm = 0; fm < 2; ++fm) {
#pragma unroll
        for (int r = 0; r < 4; ++r) {
            int rloc = wr * 32 + fm * 16 + cq * 4 + r;
            if (row0 + rloc < rows_g) {
                size_t orow = (size_t)s_orow[rloc];
#pragma unroll
                for (int fn = 0; fn < 2; ++fn) {
                    int col = n0 + wc * 32 + fn * 16 + cr;
                    float gv = acc[0][fm][fn][r];
                    float uv = acc[1][fm][fn][r];
                    float sv = gv / (1.0f + expf(-gv));
                    actPtr[orow * IDIM + col] = f2bf(sv * uv);
                }
            }
        }
    }
}

// ---------------- grouped GEMM2: y = act @ Wdown ----------------
__global__ __launch_bounds__(256)
void gemm2_kernel(const unsigned short* __restrict__ actB,
                  const unsigned short* __restrict__ actE,
                  const float* __restrict__ base_dn,
                  const float* __restrict__ exp_dn,
                  const int* __restrict__ tmap,
                  const int* __restrict__ list,
                  float* __restrict__ outB,
                  float* __restrict__ yslot) {
    __shared__ unsigned short lds_a[64 * 40];
    __shared__ unsigned short lds_b[64 * 40];
    __shared__ int s_row[64];
    __shared__ int sh[20];

    int tid = threadIdx.x;
    if (tid < 20) sh[tid] = tmap[tid];
    __syncthreads();
    int rt = blockIdx.x;
    if (rt >= sh[9]) return;
    int g = 0;
    while (rt >= sh[g + 1]) ++g;
    int rows_g = sh[10 + g];
    int row0 = (rt - sh[g]) * 64;
    int n0 = blockIdx.y * 64;

    if (tid < 64) {
        int r = row0 + tid;
        int rowi = -1;
        if (r < rows_g) rowi = (g == 0) ? r : list[(g - 1) * TT + r];
        s_row[tid] = rowi;
    }
    __syncthreads();

    const unsigned short* abase = (g == 0) ? actB : actE;
    const float* W = (g == 0) ? base_dn : (exp_dn + (size_t)(g - 1) * IDIM * H);
    float* obase = (g == 0) ? outB : yslot;

    int my_row = s_row[tid >> 2];
    const unsigned short* ap = abase + (size_t)(my_row < 0 ? 0 : my_row) * IDIM + (tid & 3) * 8;
    int a_lds = (tid >> 2) * 40 + (tid & 3) * 8;

    int bs = tid & 63;
    int bkk = (bs >> 4) << 3;
    int bnq = bs & 15;
    const float* wp = W + (size_t)bkk * H + n0 + bnq * 4;

    int wave = tid >> 6, lane = tid & 63;
    int wr = wave >> 1, wc = wave & 1;
    int a_off0 = (wr * 32 + (lane & 15)) * 40 + (lane >> 4) * 8;
    int b_off0 = (wc * 32 + (lane & 15)) * 40 + (lane >> 4) * 8;

    f32x4 acc[2][2];
#pragma unroll
    for (int fm = 0; fm < 2; ++fm)
#pragma unroll
        for (int fn = 0; fn < 2; ++fn)
            acc[fm][fn] = (f32x4)(0.0f);

    for (int k0 = 0; k0 < IDIM; k0 += 32) {
        uint4 av = make_uint4(0, 0, 0, 0);
        if (my_row >= 0) av = *reinterpret_cast<const uint4*>(ap + k0);
        *reinterpret_cast<uint4*>(&lds_a[a_lds]) = av;

        if (tid < 64) {
            const float* wpk = wp + (size_t)k0 * H;
            float wq[8][4];
#pragma unroll
            for (int r = 0; r < 8; ++r) {
                float4 t4 = *reinterpret_cast<const float4*>(wpk + (size_t)r * H);
                wq[r][0] = t4.x; wq[r][1] = t4.y; wq[r][2] = t4.z; wq[r][3] = t4.w;
            }
#pragma unroll
            for (int c = 0; c < 4; ++c) {
                unsigned int p0 = (unsigned)f2bf(wq[0][c]) | ((unsigned)f2bf(wq[1][c]) << 16);
                unsigned int p1 = (unsigned)f2bf(wq[2][c]) | ((unsigned)f2bf(wq[3][c]) << 16);
                unsigned int p2 = (unsigned)f2bf(wq[4][c]) | ((unsigned)f2bf(wq[5][c]) << 16);
                unsigned int p3 = (unsigned)f2bf(wq[6][c]) | ((unsigned)f2bf(wq[7][c]) << 16);
                uint4 pk; pk.x = p0; pk.y = p1; pk.z = p2; pk.w = p3;
                *reinterpret_cast<uint4*>(&lds_b[(bnq * 4 + c) * 40 + bkk]) = pk;
            }
        }
        __syncthreads();

        bf16x8 afr[2];
#pragma unroll
        for (int fm = 0; fm < 2; ++fm)
            afr[fm] = *reinterpret_cast<const bf16x8*>(&lds_a[a_off0 + fm * 16 * 40]);
#pragma unroll
        for (int fn = 0; fn < 2; ++fn) {
            bf16x8 bfr = *reinterpret_cast<const bf16x8*>(&lds_b[b_off0 + fn * 16 * 40]);
#pragma unroll
            for (int fm = 0; fm < 2; ++fm)
                acc[fm][fn] = __builtin_amdgcn_mfma_f32_16x16x32_bf16(
                    afr[fm], bfr, acc[fm][fn], 0, 0, 0);
        }
        __syncthreads();
    }

    int cq = lane >> 4, cr = lane & 15;
#pragma unroll
    for (int fm = 0; fm < 2; ++fm) {
#pragma unroll
        for (int r = 0; r < 4; ++r) {
            int rloc = wr * 32 + fm * 16 + cq * 4 + r;
            if (row0 + rloc < rows_g) {
                size_t orow = (size_t)s_row[rloc];
#pragma unroll
                for (int fn = 0; fn < 2; ++fn) {
                    int col = n0 + wc * 32 + fn * 16 + cr;
                    obase[orow * H + col] = acc[fm][fn][r];
                }
            }
        }
    }
}

// ---------------- combine: out += w0*y0 + w1*y1 ----------------
__global__ void combine_kernel(float* __restrict__ out, const float* __restrict__ yslot,
                               const float* __restrict__ topw) {
    int i = blockIdx.x * blockDim.x + threadIdx.x;   // float4 index, total T*H/4
    int t = i >> 9;                                  // H/4 = 512
    int c = (i & 511) << 2;
    float w0 = topw[t * 2], w1 = topw[t * 2 + 1];
    float4 y0 = *reinterpret_cast<const float4*>(yslot + ((size_t)(2 * t) * H + c));
    float4 y1 = *reinterpret_cast<const float4*>(yslot + ((size_t)(2 * t + 1) * H + c));
    float4* po = reinterpret_cast<float4*>(out + ((size_t)t * H + c));
    float4 o = *po;
    o.x += w0 * y0.x + w1 * y1.x;
    o.y += w0 * y0.y + w1 * y1.y;
    o.z += w0 * y0.z + w1 * y1.z;
    o.w += w0 * y0.w + w1 * y1.w;
    *po = o;
}

extern "C" void kernel_launch(void* const* d_in, const int* in_sizes, int n_in,
                              void* d_out, int out_size, void* d_ws, size_t ws_size,
                              hipStream_t stream) {
    const float* x   = (const float*)d_in[0];
    const float* gw  = (const float*)d_in[1];
    const float* bgu = (const float*)d_in[2];
    const float* bdn = (const float*)d_in[3];
    const float* egu = (const float*)d_in[4];
    const float* edn = (const float*)d_in[5];
    float* out = (float*)d_out;
    char* ws = (char*)d_ws;

    unsigned short* xb   = (unsigned short*)(ws + 0);          //  8,388,608 B
    unsigned short* actB = (unsigned short*)(ws + 8388608);    // 23,068,672 B
    unsigned short* actE = (unsigned short*)(ws + 31457280);   // 46,137,344 B
    float* yslot         = (float*)(ws + 77594624);            // 33,554,432 B
    float* topw          = (float*)(ws + 111149056);           //     16,384 B
    int* cnt             = (int*)(ws + 111165440);             //        256 B
    int* list            = (int*)(ws + 111165696);             //     65,536 B
    int* tmap            = (int*)(ws + 111231232);             //        256 B

    hipMemsetAsync(cnt, 0, NE * sizeof(int), stream);
    cvt_x_kernel<<<4096, 256, 0, stream>>>(x, xb);
    router_kernel<<<TT, 64, 0, stream>>>(x, gw, topw, cnt, list);
    setup_kernel<<<1, 64, 0, stream>>>(cnt, tmap);
    // max row tiles: base 32 + experts (4096/64 + 8) = 104
    gemm1_kernel<<<dim3(104, IDIM / 64), 256, 0, stream>>>(xb, bgu, egu, tmap, list, actB, actE);
    gemm2_kernel<<<dim3(104, H / 64), 256, 0, stream>>>(actB, actE, bdn, edn, tmap, list, out, yslot);
    combine_kernel<<<4096, 256, 0, stream>>>(out, yslot, topw);
}

// Round 2
// 1320.535 us; speedup vs baseline: 1.3840x; 1.3840x over previous
//
#include <hip/hip_runtime.h>
#include <math.h>

#define H 2048
#define IDIM 5632
#define NE 8
#define TT 2048            // tokens = 2*1024
#define LDW1 (2 * IDIM)    // 11264

typedef __bf16 bf16x8 __attribute__((ext_vector_type(8)));
typedef float f32x4 __attribute__((ext_vector_type(4)));

__device__ __forceinline__ unsigned short f2bf(float f) {
    unsigned int u = __builtin_bit_cast(unsigned int, f);
    u += 0x7FFFu + ((u >> 16) & 1u);   // round-to-nearest-even
    return (unsigned short)(u >> 16);
}

__device__ __forceinline__ void gload_lds16(const void* g, void* l) {
    __builtin_amdgcn_global_load_lds(
        (const __attribute__((address_space(1))) void*)g,
        (__attribute__((address_space(3))) void*)l, 16, 0, 0);
}

// ---------------- x (fp32) -> bf16 ----------------
__global__ void cvt_x_kernel(const float* __restrict__ x, unsigned short* __restrict__ xb) {
    int i = blockIdx.x * blockDim.x + threadIdx.x;
    float4 v = reinterpret_cast<const float4*>(x)[i];
    ushort4 o;
    o.x = f2bf(v.x); o.y = f2bf(v.y); o.z = f2bf(v.z); o.w = f2bf(v.w);
    reinterpret_cast<ushort4*>(xb)[i] = o;
}

// ---------------- router: fp64 logits, softmax, top-2, lists ----------------
__global__ void router_kernel(const float* __restrict__ x, const float* __restrict__ gw,
                              float* __restrict__ topw, int* __restrict__ cnt,
                              int* __restrict__ list) {
    int t = blockIdx.x;
    int lane = threadIdx.x;
    const float* xt = x + (size_t)t * H;
    double acc[NE];
#pragma unroll
    for (int e = 0; e < NE; ++e) acc[e] = 0.0;
    for (int h = lane; h < H; h += 64) {
        float xv = xt[h];
#pragma unroll
        for (int e = 0; e < NE; ++e) acc[e] += (double)xv * (double)gw[e * H + h];
    }
#pragma unroll
    for (int e = 0; e < NE; ++e) {
#pragma unroll
        for (int off = 32; off > 0; off >>= 1)
            acc[e] += __shfl_xor(acc[e], off, 64);
    }
    if (lane == 0) {
        double mx = acc[0];
#pragma unroll
        for (int e = 1; e < NE; ++e) mx = acc[e] > mx ? acc[e] : mx;
        double ex[NE], s = 0.0;
#pragma unroll
        for (int e = 0; e < NE; ++e) { ex[e] = exp(acc[e] - mx); s += ex[e]; }
        int e0 = 0; double b0 = ex[0];
#pragma unroll
        for (int e = 1; e < NE; ++e) if (ex[e] > b0) { b0 = ex[e]; e0 = e; }
        int e1 = -1; double b1 = -1.0;
#pragma unroll
        for (int e = 0; e < NE; ++e) if (e != e0 && ex[e] > b1) { b1 = ex[e]; e1 = e; }
        float p0 = (float)(b0 / s), p1 = (float)(b1 / s);
        float w0 = p0 / (p0 + p1), w1 = p1 / (p0 + p1);
        topw[t * 2 + 0] = w0;
        topw[t * 2 + 1] = w1;
        int pos0 = atomicAdd(&cnt[e0], 1); list[e0 * TT + pos0] = t * 2 + 0;
        int pos1 = atomicAdd(&cnt[e1], 1); list[e1 * TT + pos1] = t * 2 + 1;
    }
}

// ---------------- tile map: group tile prefix sums (128-row tiles) ----------------
__global__ void setup_kernel(const int* __restrict__ cnt, int* __restrict__ tmap) {
    if (threadIdx.x == 0) {
        int acc0 = 0;
        tmap[0] = 0;
        for (int g = 0; g < 9; ++g) {
            int rows = (g == 0) ? TT : cnt[g - 1];
            tmap[10 + g] = rows;
            acc0 += (rows + 127) >> 7;
            tmap[g + 1] = acc0;
        }
        tmap[19] = 0;
    }
}

// ---------------- grouped GEMM1: 128 rows x 64 act-cols (=128 wcols), BK=64 ----------------
// LDS A: [128 rows][8 kc], byte = row*128 + (kc ^ (row&7))*16   (content: A[row][kc*8..])
// LDS B: [128 cols][8 kc], byte = c*128   + (kc ^ (c&7))*16
// col interleave: c -> half=(c>>5)&1 (0:gate 1:up), acol = n0 + (c>>6)*32 + (c&31)
__global__ __launch_bounds__(256)
void gemm1_kernel(const unsigned short* __restrict__ xb,
                  const float* __restrict__ base_gu,
                  const float* __restrict__ exp_gu,
                  const int* __restrict__ tmap,
                  const int* __restrict__ list,
                  unsigned short* __restrict__ actB,
                  unsigned short* __restrict__ actE) {
    __shared__ unsigned short lds_a[128 * 64];
    __shared__ unsigned short lds_b[128 * 64];
    __shared__ int s_arow[128];
    __shared__ int s_orow[128];
    __shared__ int sh[20];

    int tid = threadIdx.x;
    if (tid < 20) sh[tid] = tmap[tid];
    __syncthreads();
    if (blockIdx.x >= sh[9]) return;
    int rt = blockIdx.x;
    int g = 0;
    while (rt >= sh[g + 1]) ++g;
    int rows_g = sh[10 + g];
    int row0 = (rt - sh[g]) * 128;
    int n0 = blockIdx.y * 64;

    if (tid < 128) {
        int r = row0 + tid;
        int arow = 0, orow = 0;
        if (r < rows_g) {
            if (g == 0) { arow = r; orow = r; }
            else { int e = list[(g - 1) * TT + r]; arow = e >> 1; orow = e; }
        }
        s_arow[tid] = arow;
        s_orow[tid] = orow;
    }
    __syncthreads();

    const float* W = (g == 0) ? base_gu : (exp_gu + (size_t)(g - 1) * H * LDW1);
    unsigned short* actPtr = (g == 0) ? actB : actE;

    // A staging: issue i covers rows i*32..i*32+31; thread -> row_l=tid>>3, kc=tid&7
    int arow_l = tid >> 3;
    int akc = tid & 7;
    int asw = akc ^ (arow_l & 7);
    const unsigned short* asrc[4];
#pragma unroll
    for (int i = 0; i < 4; ++i)
        asrc[i] = xb + (size_t)s_arow[i * 32 + arow_l] * H + asw * 8;
    char* adst = (char*)lds_a + (tid & 192) * 16;   // wave-uniform; HW adds lane*16

    // B staging: thread -> 4 cols c0..c0+3, 8 k's at kcB*8
    int cg = tid & 31;
    int kcB = tid >> 5;                 // 0..7
    int c0 = cg * 4;
    int halfB = (c0 >> 5) & 1;
    int acol0 = n0 + ((c0 >> 6) << 5) + (c0 & 31);
    const float* wp = W + (size_t)(halfB ? IDIM : 0) + acol0;
    int bwaddr[4];
#pragma unroll
    for (int j = 0; j < 4; ++j)
        bwaddr[j] = (c0 + j) * 128 + ((kcB ^ ((c0 + j) & 7)) << 4);

    int wave = tid >> 6, lane = tid & 63;
    int wr = wave >> 1, wc = wave & 1;
    int arow_f = wr * 64 + (lane & 15);
    int bcol_f = wc * 64 + (lane & 15);
    int axor = arow_f & 7;
    int bxor = bcol_f & 7;
    int kq = lane >> 4;

    f32x4 acc[4][4];
#pragma unroll
    for (int fm = 0; fm < 4; ++fm)
#pragma unroll
        for (int fn = 0; fn < 4; ++fn)
            acc[fm][fn] = (f32x4)(0.0f);

    for (int k0 = 0; k0 < H; k0 += 64) {
#pragma unroll
        for (int i = 0; i < 4; ++i)
            gload_lds16(asrc[i] + k0, adst + i * 4096);

        const float* wk = wp + (size_t)(k0 + kcB * 8) * LDW1;
        float bv[8][4];
#pragma unroll
        for (int r = 0; r < 8; ++r) {
            float4 t4 = *reinterpret_cast<const float4*>(wk + (size_t)r * LDW1);
            bv[r][0] = t4.x; bv[r][1] = t4.y; bv[r][2] = t4.z; bv[r][3] = t4.w;
        }
#pragma unroll
        for (int j = 0; j < 4; ++j) {
            uint4 pk;
            pk.x = (unsigned)f2bf(bv[0][j]) | ((unsigned)f2bf(bv[1][j]) << 16);
            pk.y = (unsigned)f2bf(bv[2][j]) | ((unsigned)f2bf(bv[3][j]) << 16);
            pk.z = (unsigned)f2bf(bv[4][j]) | ((unsigned)f2bf(bv[5][j]) << 16);
            pk.w = (unsigned)f2bf(bv[6][j]) | ((unsigned)f2bf(bv[7][j]) << 16);
            *reinterpret_cast<uint4*>((char*)lds_b + bwaddr[j]) = pk;
        }
        __syncthreads();

#pragma unroll
        for (int ks = 0; ks < 2; ++ks) {
            int kc = kq + ks * 4;
            bf16x8 af[4];
#pragma unroll
            for (int fm = 0; fm < 4; ++fm)
                af[fm] = *reinterpret_cast<const bf16x8*>(
                    (char*)lds_a + (arow_f + fm * 16) * 128 + ((kc ^ axor) << 4));
#pragma unroll
            for (int fn = 0; fn < 4; ++fn) {
                bf16x8 bf = *reinterpret_cast<const bf16x8*>(
                    (char*)lds_b + (bcol_f + fn * 16) * 128 + ((kc ^ bxor) << 4));
#pragma unroll
                for (int fm = 0; fm < 4; ++fm)
                    acc[fm][fn] = __builtin_amdgcn_mfma_f32_16x16x32_bf16(
                        af[fm], bf, acc[fm][fn], 0, 0, 0);
            }
        }
        __syncthreads();
    }

    int cq = lane >> 4, cr = lane & 15;
#pragma unroll
    for (int fm = 0; fm < 4; ++fm) {
#pragma unroll
        for (int r = 0; r < 4; ++r) {
            int rloc = wr * 64 + fm * 16 + cq * 4 + r;
            if (row0 + rloc < rows_g) {
                size_t orow = (size_t)s_orow[rloc];
#pragma unroll
                for (int fn = 0; fn < 2; ++fn) {
                    float gv = acc[fm][fn][r];
                    float uv = acc[fm][fn + 2][r];
                    float sv = gv / (1.0f + __expf(-gv));
                    int col = n0 + wc * 32 + fn * 16 + cr;
                    actPtr[orow * IDIM + col] = f2bf(sv * uv);
                }
            }
        }
    }
}

// ---------------- grouped GEMM2: 128 rows x 128 cols, BK=64 ----------------
__global__ __launch_bounds__(256)
void gemm2_kernel(const unsigned short* __restrict__ actB,
                  const unsigned short* __restrict__ actE,
                  const float* __restrict__ base_dn,
                  const float* __restrict__ exp_dn,
                  const int* __restrict__ tmap,
                  const int* __restrict__ list,
                  float* __restrict__ outB,
                  float* __restrict__ yslot) {
    __shared__ unsigned short lds_a[128 * 64];
    __shared__ unsigned short lds_b[128 * 64];
    __shared__ int s_row[128];
    __shared__ int sh[20];

    int tid = threadIdx.x;
    if (tid < 20) sh[tid] = tmap[tid];
    __syncthreads();
    if (blockIdx.x >= sh[9]) return;
    int rt = blockIdx.x;
    int g = 0;
    while (rt >= sh[g + 1]) ++g;
    int rows_g = sh[10 + g];
    int row0 = (rt - sh[g]) * 128;
    int n0 = blockIdx.y * 128;

    if (tid < 128) {
        int r = row0 + tid;
        int rowi = 0;
        if (r < rows_g) rowi = (g == 0) ? r : list[(g - 1) * TT + r];
        s_row[tid] = rowi;
    }
    __syncthreads();

    const unsigned short* abase = (g == 0) ? actB : actE;
    const float* W = (g == 0) ? base_dn : (exp_dn + (size_t)(g - 1) * IDIM * H);
    float* obase = (g == 0) ? outB : yslot;

    int arow_l = tid >> 3;
    int akc = tid & 7;
    int asw = akc ^ (arow_l & 7);
    const unsigned short* asrc[4];
#pragma unroll
    for (int i = 0; i < 4; ++i)
        asrc[i] = abase + (size_t)s_row[i * 32 + arow_l] * IDIM + asw * 8;
    char* adst = (char*)lds_a + (tid & 192) * 16;

    int cg = tid & 31;
    int kcB = tid >> 5;
    int c0 = cg * 4;
    const float* wp = W + n0 + c0;
    int bwaddr[4];
#pragma unroll
    for (int j = 0; j < 4; ++j)
        bwaddr[j] = (c0 + j) * 128 + ((kcB ^ ((c0 + j) & 7)) << 4);

    int wave = tid >> 6, lane = tid & 63;
    int wr = wave >> 1, wc = wave & 1;
    int arow_f = wr * 64 + (lane & 15);
    int bcol_f = wc * 64 + (lane & 15);
    int axor = arow_f & 7;
    int bxor = bcol_f & 7;
    int kq = lane >> 4;

    f32x4 acc[4][4];
#pragma unroll
    for (int fm = 0; fm < 4; ++fm)
#pragma unroll
        for (int fn = 0; fn < 4; ++fn)
            acc[fm][fn] = (f32x4)(0.0f);

    for (int k0 = 0; k0 < IDIM; k0 += 64) {
#pragma unroll
        for (int i = 0; i < 4; ++i)
            gload_lds16(asrc[i] + k0, adst + i * 4096);

        const float* wk = wp + (size_t)(k0 + kcB * 8) * H;
        float bv[8][4];
#pragma unroll
        for (int r = 0; r < 8; ++r) {
            float4 t4 = *reinterpret_cast<const float4*>(wk + (size_t)r * H);
            bv[r][0] = t4.x; bv[r][1] = t4.y; bv[r][2] = t4.z; bv[r][3] = t4.w;
        }
#pragma unroll
        for (int j = 0; j < 4; ++j) {
            uint4 pk;
            pk.x = (unsigned)f2bf(bv[0][j]) | ((unsigned)f2bf(bv[1][j]) << 16);
            pk.y = (unsigned)f2bf(bv[2][j]) | ((unsigned)f2bf(bv[3][j]) << 16);
            pk.z = (unsigned)f2bf(bv[4][j]) | ((unsigned)f2bf(bv[5][j]) << 16);
            pk.w = (unsigned)f2bf(bv[6][j]) | ((unsigned)f2bf(bv[7][j]) << 16);
            *reinterpret_cast<uint4*>((char*)lds_b + bwaddr[j]) = pk;
        }
        __syncthreads();

#pragma unroll
        for (int ks = 0; ks < 2; ++ks) {
            int kc = kq + ks * 4;
            bf16x8 af[4];
#pragma unroll
            for (int fm = 0; fm < 4; ++fm)
                af[fm] = *reinterpret_cast<const bf16x8*>(
                    (char*)lds_a + (arow_f + fm * 16) * 128 + ((kc ^ axor) << 4));
#pragma unroll
            for (int fn = 0; fn < 4; ++fn) {
                bf16x8 bf = *reinterpret_cast<const bf16x8*>(
                    (char*)lds_b + (bcol_f + fn * 16) * 128 + ((kc ^ bxor) << 4));
#pragma unroll
                for (int fm = 0; fm < 4; ++fm)
                    acc[fm][fn] = __builtin_amdgcn_mfma_f32_16x16x32_bf16(
                        af[fm], bf, acc[fm][fn], 0, 0, 0);
            }
        }
        __syncthreads();
    }

    int cq = lane >> 4, cr = lane & 15;
#pragma unroll
    for (int fm = 0; fm < 4; ++fm) {
#pragma unroll
        for (int r = 0; r < 4; ++r) {
            int rloc = wr * 64 + fm * 16 + cq * 4 + r;
            if (row0 + rloc < rows_g) {
                size_t orow = (size_t)s_row[rloc];
#pragma unroll
                for (int fn = 0; fn < 4; ++fn) {
                    int col = n0 + wc * 64 + fn * 16 + cr;
                    obase[orow * H + col] = acc[fm][fn][r];
                }
            }
        }
    }
}

// ---------------- combine: out += w0*y0 + w1*y1 ----------------
__global__ void combine_kernel(float* __restrict__ out, const float* __restrict__ yslot,
                               const float* __restrict__ topw) {
    int i = blockIdx.x * blockDim.x + threadIdx.x;
    int t = i >> 9;
    int c = (i & 511) << 2;
    float w0 = topw[t * 2], w1 = topw[t * 2 + 1];
    float4 y0 = *reinterpret_cast<const float4*>(yslot + ((size_t)(2 * t) * H + c));
    float4 y1 = *reinterpret_cast<const float4*>(yslot + ((size_t)(2 * t + 1) * H + c));
    float4* po = reinterpret_cast<float4*>(out + ((size_t)t * H + c));
    float4 o = *po;
    o.x += w0 * y0.x + w1 * y1.x;
    o.y += w0 * y0.y + w1 * y1.y;
    o.z += w0 * y0.z + w1 * y1.z;
    o.w += w0 * y0.w + w1 * y1.w;
    *po = o;
}

extern "C" void kernel_launch(void* const* d_in, const int* in_sizes, int n_in,
                              void* d_out, int out_size, void* d_ws, size_t ws_size,
                              hipStream_t stream) {
    const float* x   = (const float*)d_in[0];
    const float* gw  = (const float*)d_in[1];
    const float* bgu = (const float*)d_in[2];
    const float* bdn = (const float*)d_in[3];
    const float* egu = (const float*)d_in[4];
    const float* edn = (const float*)d_in[5];
    float* out = (float*)d_out;
    char* ws = (char*)d_ws;

    unsigned short* xb   = (unsigned short*)(ws + 0);          //  8,388,608 B
    unsigned short* actB = (unsigned short*)(ws + 8388608);    // 23,068,672 B
    unsigned short* actE = (unsigned short*)(ws + 31457280);   // 46,137,344 B
    float* yslot         = (float*)(ws + 77594624);            // 33,554,432 B
    float* topw          = (float*)(ws + 111149056);
    int* cnt             = (int*)(ws + 111165440);
    int* list            = (int*)(ws + 111165696);
    int* tmap            = (int*)(ws + 111231232);

    hipMemsetAsync(cnt, 0, NE * sizeof(int), stream);
    cvt_x_kernel<<<4096, 256, 0, stream>>>(x, xb);
    router_kernel<<<TT, 64, 0, stream>>>(x, gw, topw, cnt, list);
    setup_kernel<<<1, 64, 0, stream>>>(cnt, tmap);
    // max 128-row tiles: base 16 + experts (4096/128 + 8) = 56
    gemm1_kernel<<<dim3(56, IDIM / 64), 256, 0, stream>>>(xb, bgu, egu, tmap, list, actB, actE);
    gemm2_kernel<<<dim3(56, H / 128), 256, 0, stream>>>(actB, actE, bdn, edn, tmap, list, out, yslot);
    combine_kernel<<<4096, 256, 0, stream>>>(out, yslot, topw);
}

// Round 3
// 1094.121 us; speedup vs baseline: 1.6704x; 1.2069x over previous
//
#include <hip/hip_runtime.h>
#include <math.h>

#define H 2048
#define IDIM 5632
#define NE 8
#define TT 2048            // tokens = 2*1024
#define LDW1 (2 * IDIM)    // 11264

typedef __bf16 bf16x8 __attribute__((ext_vector_type(8)));
typedef float f32x4 __attribute__((ext_vector_type(4)));

__device__ __forceinline__ unsigned short f2bf(float f) {
    unsigned int u = __builtin_bit_cast(unsigned int, f);
    u += 0x7FFFu + ((u >> 16) & 1u);   // round-to-nearest-even
    return (unsigned short)(u >> 16);
}

// HW convert: compiler emits v_cvt_pk_bf16_f32 from paired casts (RTNE)
__device__ __forceinline__ unsigned int pk2(float a, float b) {
    __bf16 x = (__bf16)a, y = (__bf16)b;
    unsigned short lo = __builtin_bit_cast(unsigned short, x);
    unsigned short hi = __builtin_bit_cast(unsigned short, y);
    return (unsigned int)lo | ((unsigned int)hi << 16);
}

__device__ __forceinline__ void gload_lds16(const void* g, void* l) {
    __builtin_amdgcn_global_load_lds(
        (const __attribute__((address_space(1))) void*)g,
        (__attribute__((address_space(3))) void*)l, 16, 0, 0);
}

// ---------------- x (fp32) -> bf16 ----------------
__global__ void cvt_x_kernel(const float* __restrict__ x, unsigned short* __restrict__ xb) {
    int i = blockIdx.x * blockDim.x + threadIdx.x;
    float4 v = reinterpret_cast<const float4*>(x)[i];
    ushort4 o;
    o.x = f2bf(v.x); o.y = f2bf(v.y); o.z = f2bf(v.z); o.w = f2bf(v.w);
    reinterpret_cast<ushort4*>(xb)[i] = o;
}

// ---------------- router: fp64 logits, softmax, top-2, lists ----------------
__global__ void router_kernel(const float* __restrict__ x, const float* __restrict__ gw,
                              float* __restrict__ topw, int* __restrict__ cnt,
                              int* __restrict__ list) {
    int t = blockIdx.x;
    int lane = threadIdx.x;
    const float* xt = x + (size_t)t * H;
    double acc[NE];
#pragma unroll
    for (int e = 0; e < NE; ++e) acc[e] = 0.0;
    for (int h = lane; h < H; h += 64) {
        float xv = xt[h];
#pragma unroll
        for (int e = 0; e < NE; ++e) acc[e] += (double)xv * (double)gw[e * H + h];
    }
#pragma unroll
    for (int e = 0; e < NE; ++e) {
#pragma unroll
        for (int off = 32; off > 0; off >>= 1)
            acc[e] += __shfl_xor(acc[e], off, 64);
    }
    if (lane == 0) {
        double mx = acc[0];
#pragma unroll
        for (int e = 1; e < NE; ++e) mx = acc[e] > mx ? acc[e] : mx;
        double ex[NE], s = 0.0;
#pragma unroll
        for (int e = 0; e < NE; ++e) { ex[e] = exp(acc[e] - mx); s += ex[e]; }
        int e0 = 0; double b0 = ex[0];
#pragma unroll
        for (int e = 1; e < NE; ++e) if (ex[e] > b0) { b0 = ex[e]; e0 = e; }
        int e1 = -1; double b1 = -1.0;
#pragma unroll
        for (int e = 0; e < NE; ++e) if (e != e0 && ex[e] > b1) { b1 = ex[e]; e1 = e; }
        float p0 = (float)(b0 / s), p1 = (float)(b1 / s);
        float w0 = p0 / (p0 + p1), w1 = p1 / (p0 + p1);
        topw[t * 2 + 0] = w0;
        topw[t * 2 + 1] = w1;
        int pos0 = atomicAdd(&cnt[e0], 1); list[e0 * TT + pos0] = t * 2 + 0;
        int pos1 = atomicAdd(&cnt[e1], 1); list[e1 * TT + pos1] = t * 2 + 1;
    }
}

// ---------------- tile map: group tile prefix sums (128-row tiles) ----------------
__global__ void setup_kernel(const int* __restrict__ cnt, int* __restrict__ tmap) {
    if (threadIdx.x == 0) {
        int acc0 = 0;
        tmap[0] = 0;
        for (int g = 0; g < 9; ++g) {
            int rows = (g == 0) ? TT : cnt[g - 1];
            tmap[10 + g] = rows;
            acc0 += (rows + 127) >> 7;
            tmap[g + 1] = acc0;
        }
        tmap[19] = 0;
    }
}

// ---------------- grouped GEMM1: 128 rows x 64 act-cols (=128 wcols), BK=64 ----------------
// XCD-pinned 1D grid: id -> xcd=id&7, s=id>>3, col j=(s/56)*8+xcd, rt=s%56
__global__ __launch_bounds__(256)
void gemm1_kernel(const unsigned short* __restrict__ xb,
                  const float* __restrict__ base_gu,
                  const float* __restrict__ exp_gu,
                  const int* __restrict__ tmap,
                  const int* __restrict__ list,
                  unsigned short* __restrict__ actB,
                  unsigned short* __restrict__ actE) {
    __shared__ unsigned short lds_a[128 * 64];
    __shared__ unsigned short lds_b[128 * 64];
    __shared__ int s_arow[128];
    __shared__ int s_orow[128];
    __shared__ int sh[20];

    int tid = threadIdx.x;
    if (tid < 20) sh[tid] = tmap[tid];
    __syncthreads();
    int id = blockIdx.x;
    int xcd = id & 7, sflat = id >> 3;
    int jcol = (sflat / 56) * 8 + xcd;
    int rt = sflat % 56;
    if (rt >= sh[9]) return;
    int g = 0;
    while (rt >= sh[g + 1]) ++g;
    int rows_g = sh[10 + g];
    int row0 = (rt - sh[g]) * 128;
    int n0 = jcol * 64;

    if (tid < 128) {
        int r = row0 + tid;
        int arow = 0, orow = 0;
        if (r < rows_g) {
            if (g == 0) { arow = r; orow = r; }
            else { int e = list[(g - 1) * TT + r]; arow = e >> 1; orow = e; }
        }
        s_arow[tid] = arow;
        s_orow[tid] = orow;
    }
    __syncthreads();

    const float* W = (g == 0) ? base_gu : (exp_gu + (size_t)(g - 1) * H * LDW1);
    unsigned short* actPtr = (g == 0) ? actB : actE;

    // A staging: issue i covers rows i*32..i*32+31; thread -> row_l=tid>>3, kc=tid&7
    int arow_l = tid >> 3;
    int akc = tid & 7;
    int asw = akc ^ (arow_l & 7);
    const unsigned short* asrc[4];
#pragma unroll
    for (int i = 0; i < 4; ++i)
        asrc[i] = xb + (size_t)s_arow[i * 32 + arow_l] * H + asw * 8;
    char* adst = (char*)lds_a + (tid & 192) * 16;   // wave-uniform; HW adds lane*16

    // B staging: thread -> 4 cols c0..c0+3, rows kcB*8..+7
    int cg = tid & 31;
    int kcB = tid >> 5;                 // 0..7
    int c0 = cg * 4;
    int halfB = (c0 >> 5) & 1;
    int acol0 = n0 + ((c0 >> 6) << 5) + (c0 & 31);
    const float* wp = W + (size_t)(halfB ? IDIM : 0) + acol0 + (size_t)kcB * 8 * LDW1;
    int bwaddr[4];
#pragma unroll
    for (int j = 0; j < 4; ++j)
        bwaddr[j] = (c0 + j) * 128 + ((kcB ^ ((c0 + j) & 7)) << 4);

    int wave = tid >> 6, lane = tid & 63;
    int wr = wave >> 1, wc = wave & 1;
    int arow_f = wr * 64 + (lane & 15);
    int bcol_f = wc * 64 + (lane & 15);
    int axor = arow_f & 7;
    int bxor = bcol_f & 7;
    int kq = lane >> 4;

    f32x4 acc[4][4];
#pragma unroll
    for (int fm = 0; fm < 4; ++fm)
#pragma unroll
        for (int fn = 0; fn < 4; ++fn)
            acc[fm][fn] = (f32x4)(0.0f);

    float4 rA[8], rB[8];
#pragma unroll
    for (int r = 0; r < 8; ++r)
        rA[r] = *reinterpret_cast<const float4*>(wp + (size_t)r * LDW1);

    auto STEP = [&](int k0, float4* rc, float4* rn, bool loadnext) {
#pragma unroll
        for (int i = 0; i < 4; ++i)
            gload_lds16(asrc[i] + k0, adst + i * 4096);
        if (loadnext) {
            const float* wn = wp + (size_t)(k0 + 64) * LDW1;
#pragma unroll
            for (int r = 0; r < 8; ++r)
                rn[r] = *reinterpret_cast<const float4*>(wn + (size_t)r * LDW1);
        }
#pragma unroll
        for (int j = 0; j < 4; ++j) {
            uint4 pk;
            pk.x = pk2(((const float*)&rc[0])[j], ((const float*)&rc[1])[j]);
            pk.y = pk2(((const float*)&rc[2])[j], ((const float*)&rc[3])[j]);
            pk.z = pk2(((const float*)&rc[4])[j], ((const float*)&rc[5])[j]);
            pk.w = pk2(((const float*)&rc[6])[j], ((const float*)&rc[7])[j]);
            *reinterpret_cast<uint4*>((char*)lds_b + bwaddr[j]) = pk;
        }
        if (loadnext) asm volatile("s_waitcnt vmcnt(8) lgkmcnt(0)" ::: "memory");
        else          asm volatile("s_waitcnt vmcnt(0) lgkmcnt(0)" ::: "memory");
        __builtin_amdgcn_sched_barrier(0);
        __builtin_amdgcn_s_barrier();
        __builtin_amdgcn_sched_barrier(0);
#pragma unroll
        for (int ks = 0; ks < 2; ++ks) {
            int kc = kq + ks * 4;
            bf16x8 af[4];
#pragma unroll
            for (int fm = 0; fm < 4; ++fm)
                af[fm] = *reinterpret_cast<const bf16x8*>(
                    (char*)lds_a + (arow_f + fm * 16) * 128 + ((kc ^ axor) << 4));
#pragma unroll
            for (int fn = 0; fn < 4; ++fn) {
                bf16x8 bf = *reinterpret_cast<const bf16x8*>(
                    (char*)lds_b + (bcol_f + fn * 16) * 128 + ((kc ^ bxor) << 4));
#pragma unroll
                for (int fm = 0; fm < 4; ++fm)
                    acc[fm][fn] = __builtin_amdgcn_mfma_f32_16x16x32_bf16(
                        af[fm], bf, acc[fm][fn], 0, 0, 0);
            }
        }
        __builtin_amdgcn_sched_barrier(0);
        __builtin_amdgcn_s_barrier();
        __builtin_amdgcn_sched_barrier(0);
    };

    for (int k0 = 0; k0 < H; k0 += 128) {
        STEP(k0, rA, rB, true);
        STEP(k0 + 64, rB, rA, k0 + 128 < H);
    }

    int cq = lane >> 4, cr = lane & 15;
#pragma unroll
    for (int fm = 0; fm < 4; ++fm) {
#pragma unroll
        for (int r = 0; r < 4; ++r) {
            int rloc = wr * 64 + fm * 16 + cq * 4 + r;
            if (row0 + rloc < rows_g) {
                size_t orow = (size_t)s_orow[rloc];
#pragma unroll
                for (int fn = 0; fn < 2; ++fn) {
                    float gv = acc[fm][fn][r];
                    float uv = acc[fm][fn + 2][r];
                    float sv = gv / (1.0f + __expf(-gv));
                    int col = n0 + wc * 32 + fn * 16 + cr;
                    actPtr[orow * IDIM + col] = f2bf(sv * uv);
                }
            }
        }
    }
}

// ---------------- grouped GEMM2: 128 rows x 128 cols, BK=64 ----------------
__global__ __launch_bounds__(256)
void gemm2_kernel(const unsigned short* __restrict__ actB,
                  const unsigned short* __restrict__ actE,
                  const float* __restrict__ base_dn,
                  const float* __restrict__ exp_dn,
                  const int* __restrict__ tmap,
                  const int* __restrict__ list,
                  float* __restrict__ outB,
                  float* __restrict__ yslot) {
    __shared__ unsigned short lds_a[128 * 64];
    __shared__ unsigned short lds_b[128 * 64];
    __shared__ int s_row[128];
    __shared__ int sh[20];

    int tid = threadIdx.x;
    if (tid < 20) sh[tid] = tmap[tid];
    __syncthreads();
    int id = blockIdx.x;
    int xcd = id & 7, sflat = id >> 3;
    int jcol = (sflat / 56) * 8 + xcd;
    int rt = sflat % 56;
    if (rt >= sh[9]) return;
    int g = 0;
    while (rt >= sh[g + 1]) ++g;
    int rows_g = sh[10 + g];
    int row0 = (rt - sh[g]) * 128;
    int n0 = jcol * 128;

    if (tid < 128) {
        int r = row0 + tid;
        int rowi = 0;
        if (r < rows_g) rowi = (g == 0) ? r : list[(g - 1) * TT + r];
        s_row[tid] = rowi;
    }
    __syncthreads();

    const unsigned short* abase = (g == 0) ? actB : actE;
    const float* W = (g == 0) ? base_dn : (exp_dn + (size_t)(g - 1) * IDIM * H);
    float* obase = (g == 0) ? outB : yslot;

    int arow_l = tid >> 3;
    int akc = tid & 7;
    int asw = akc ^ (arow_l & 7);
    const unsigned short* asrc[4];
#pragma unroll
    for (int i = 0; i < 4; ++i)
        asrc[i] = abase + (size_t)s_row[i * 32 + arow_l] * IDIM + asw * 8;
    char* adst = (char*)lds_a + (tid & 192) * 16;

    int cg = tid & 31;
    int kcB = tid >> 5;
    int c0 = cg * 4;
    const float* wp = W + n0 + c0 + (size_t)kcB * 8 * H;
    int bwaddr[4];
#pragma unroll
    for (int j = 0; j < 4; ++j)
        bwaddr[j] = (c0 + j) * 128 + ((kcB ^ ((c0 + j) & 7)) << 4);

    int wave = tid >> 6, lane = tid & 63;
    int wr = wave >> 1, wc = wave & 1;
    int arow_f = wr * 64 + (lane & 15);
    int bcol_f = wc * 64 + (lane & 15);
    int axor = arow_f & 7;
    int bxor = bcol_f & 7;
    int kq = lane >> 4;

    f32x4 acc[4][4];
#pragma unroll
    for (int fm = 0; fm < 4; ++fm)
#pragma unroll
        for (int fn = 0; fn < 4; ++fn)
            acc[fm][fn] = (f32x4)(0.0f);

    float4 rA[8], rB[8];
#pragma unroll
    for (int r = 0; r < 8; ++r)
        rA[r] = *reinterpret_cast<const float4*>(wp + (size_t)r * H);

    auto STEP = [&](int k0, float4* rc, float4* rn, bool loadnext) {
#pragma unroll
        for (int i = 0; i < 4; ++i)
            gload_lds16(asrc[i] + k0, adst + i * 4096);
        if (loadnext) {
            const float* wn = wp + (size_t)(k0 + 64) * H;
#pragma unroll
            for (int r = 0; r < 8; ++r)
                rn[r] = *reinterpret_cast<const float4*>(wn + (size_t)r * H);
        }
#pragma unroll
        for (int j = 0; j < 4; ++j) {
            uint4 pk;
            pk.x = pk2(((const float*)&rc[0])[j], ((const float*)&rc[1])[j]);
            pk.y = pk2(((const float*)&rc[2])[j], ((const float*)&rc[3])[j]);
            pk.z = pk2(((const float*)&rc[4])[j], ((const float*)&rc[5])[j]);
            pk.w = pk2(((const float*)&rc[6])[j], ((const float*)&rc[7])[j]);
            *reinterpret_cast<uint4*>((char*)lds_b + bwaddr[j]) = pk;
        }
        if (loadnext) asm volatile("s_waitcnt vmcnt(8) lgkmcnt(0)" ::: "memory");
        else          asm volatile("s_waitcnt vmcnt(0) lgkmcnt(0)" ::: "memory");
        __builtin_amdgcn_sched_barrier(0);
        __builtin_amdgcn_s_barrier();
        __builtin_amdgcn_sched_barrier(0);
#pragma unroll
        for (int ks = 0; ks < 2; ++ks) {
            int kc = kq + ks * 4;
            bf16x8 af[4];
#pragma unroll
            for (int fm = 0; fm < 4; ++fm)
                af[fm] = *reinterpret_cast<const bf16x8*>(
                    (char*)lds_a + (arow_f + fm * 16) * 128 + ((kc ^ axor) << 4));
#pragma unroll
            for (int fn = 0; fn < 4; ++fn) {
                bf16x8 bf = *reinterpret_cast<const bf16x8*>(
                    (char*)lds_b + (bcol_f + fn * 16) * 128 + ((kc ^ bxor) << 4));
#pragma unroll
                for (int fm = 0; fm < 4; ++fm)
                    acc[fm][fn] = __builtin_amdgcn_mfma_f32_16x16x32_bf16(
                        af[fm], bf, acc[fm][fn], 0, 0, 0);
            }
        }
        __builtin_amdgcn_sched_barrier(0);
        __builtin_amdgcn_s_barrier();
        __builtin_amdgcn_sched_barrier(0);
    };

    for (int k0 = 0; k0 < IDIM; k0 += 128) {
        STEP(k0, rA, rB, true);
        STEP(k0 + 64, rB, rA, k0 + 128 < IDIM);
    }

    int cq = lane >> 4, cr = lane & 15;
#pragma unroll
    for (int fm = 0; fm < 4; ++fm) {
#pragma unroll
        for (int r = 0; r < 4; ++r) {
            int rloc = wr * 64 + fm * 16 + cq * 4 + r;
            if (row0 + rloc < rows_g) {
                size_t orow = (size_t)s_row[rloc];
#pragma unroll
                for (int fn = 0; fn < 4; ++fn) {
                    int col = n0 + wc * 64 + fn * 16 + cr;
                    obase[orow * H + col] = acc[fm][fn][r];
                }
            }
        }
    }
}

// ---------------- combine: out += w0*y0 + w1*y1 ----------------
__global__ void combine_kernel(float* __restrict__ out, const float* __restrict__ yslot,
                               const float* __restrict__ topw) {
    int i = blockIdx.x * blockDim.x + threadIdx.x;
    int t = i >> 9;
    int c = (i & 511) << 2;
    float w0 = topw[t * 2], w1 = topw[t * 2 + 1];
    float4 y0 = *reinterpret_cast<const float4*>(yslot + ((size_t)(2 * t) * H + c));
    float4 y1 = *reinterpret_cast<const float4*>(yslot + ((size_t)(2 * t + 1) * H + c));
    float4* po = reinterpret_cast<float4*>(out + ((size_t)t * H + c));
    float4 o = *po;
    o.x += w0 * y0.x + w1 * y1.x;
    o.y += w0 * y0.y + w1 * y1.y;
    o.z += w0 * y0.z + w1 * y1.z;
    o.w += w0 * y0.w + w1 * y1.w;
    *po = o;
}

extern "C" void kernel_launch(void* const* d_in, const int* in_sizes, int n_in,
                              void* d_out, int out_size, void* d_ws, size_t ws_size,
                              hipStream_t stream) {
    const float* x   = (const float*)d_in[0];
    const float* gw  = (const float*)d_in[1];
    const float* bgu = (const float*)d_in[2];
    const float* bdn = (const float*)d_in[3];
    const float* egu = (const float*)d_in[4];
    const float* edn = (const float*)d_in[5];
    float* out = (float*)d_out;
    char* ws = (char*)d_ws;

    unsigned short* xb   = (unsigned short*)(ws + 0);          //  8,388,608 B
    unsigned short* actB = (unsigned short*)(ws + 8388608);    // 23,068,672 B
    unsigned short* actE = (unsigned short*)(ws + 31457280);   // 46,137,344 B
    float* yslot         = (float*)(ws + 77594624);            // 33,554,432 B
    float* topw          = (float*)(ws + 111149056);
    int* cnt             = (int*)(ws + 111165440);
    int* list            = (int*)(ws + 111165696);
    int* tmap            = (int*)(ws + 111231232);

    hipMemsetAsync(cnt, 0, NE * sizeof(int), stream);
    cvt_x_kernel<<<4096, 256, 0, stream>>>(x, xb);
    router_kernel<<<TT, 64, 0, stream>>>(x, gw, topw, cnt, list);
    setup_kernel<<<1, 64, 0, stream>>>(cnt, tmap);
    // gemm1: 56 row-tiles x 88 cols, XCD-pinned flat grid (4928 = 8*11*56)
    gemm1_kernel<<<4928, 256, 0, stream>>>(xb, bgu, egu, tmap, list, actB, actE);
    // gemm2: 56 row-tiles x 16 cols, flat grid (896 = 8*2*56)
    gemm2_kernel<<<896, 256, 0, stream>>>(actB, actE, bdn, edn, tmap, list, out, yslot);
    combine_kernel<<<4096, 256, 0, stream>>>(out, yslot, topw);
}